// Round 4
// baseline (197.479 us; speedup 1.0000x reference)
//
#include <hip/hip_runtime.h>

// Register-resident fused-16 Jacobi, v7: v6 + staging-pressure fix.
//  - v6 (single dispatch, tile 128x128, 16 waves) was correct but spilled:
//    staging kept 36 transient floats live on top of 96 persistent -> peak
//    >128-reg budget -> 64 arch VGPR + scratch (WRITE 92.8MB vs 31.9 logical).
//  - v7 staging: rolling 3-row kappa window, weights row r computed as row
//    r+2 arrives; f row loaded inside the loop. Transient peak ~10 floats.
//  - kappa loaded as ONE aligned float2 per row (cols c0,c0+1):
//      center(col c0)   = q.y            (kappa[gy+1, c0+1])
//      center(col c0+1) = lane_shl1(q.x) (kappa[gy+1, c0+2]; lane63 garbage
//                                         lands on tile col 127 = halo, tight)
//      kw(col c0)       = q.x            (no DPP)
//      ke(col c0+1)     = lane_shl1(q.y) (kappa[gy+1, c0+3])
//    Fully coalesced, half the load instructions of v6's two scalar streams.
//  - step loop / LDS exchange / store identical to v6 (which passed):
//    lane owns 2 cols, wave owns 8-row strip, N/S in regs, strip edges via
//    dbuf LDS (32KB), one barrier/step, output region rel [16,112)^2.

namespace {
constexpr int    G    = 1024, Ni = 1022;
constexpr int    TOUT = 96, HALO = 16;          // tile 128
constexpr size_t IMG_K = (size_t)G * G;
constexpr size_t IMG_P = (size_t)Ni * Ni;
constexpr float  H2 = (float)(1.0 / (1023.0 * 1023.0));
}

__device__ __forceinline__ float frcp(float x) { return __builtin_amdgcn_rcpf(x); }

// lane l <- lane l-1 (wave_shr1); shifted-in lane gets 0 (bound_ctrl)
__device__ __forceinline__ float lane_shr1(float x) {
    return __builtin_bit_cast(float,
        __builtin_amdgcn_update_dpp(0, __builtin_bit_cast(int, x), 0x138, 0xF, 0xF, true));
}
// lane l <- lane l+1 (wave_shl1)
__device__ __forceinline__ float lane_shl1(float x) {
    return __builtin_bit_cast(float,
        __builtin_amdgcn_update_dpp(0, __builtin_bit_cast(int, x), 0x130, 0xF, 0xF, true));
}

__global__ __launch_bounds__(1024, 4)
void jac_fused16(const float* __restrict__ pre, float* __restrict__ out,
                 const float* __restrict__ kap, const float* __restrict__ fin)
{
    __shared__ float2 ex[2][2][1024];            // [buf][top/bot][tid] = 32 KB

    const int tid = threadIdx.x;
    const int w = tid >> 6, l = tid & 63;        // wave id (0..15), lane id
    const int bx = blockIdx.x, by = blockIdx.y, b = blockIdx.z;
    const int X0 = bx * TOUT - HALO, Y0 = by * TOUT - HALO;
    const int c0 = X0 + 2 * l;                   // lane's first column (even)
    const int gy0 = Y0 + 8 * w;                  // wave's first row

    const float* kB = kap + (size_t)b * IMG_K;
    const float* fB = fin + (size_t)b * IMG_K;
    const bool fast = (bx >= 1) && (bx <= 9) && (by >= 1) && (by <= 9);

    // ---- weights via rolling 3-row kappa window (transient peak ~10 regs) ----
    float2 wN[8], wS[8], wW[8], wE[8], Fc[8];
    if (fast) {                                  // all accesses in-bounds
        const float* kp = kB + (size_t)gy0 * G + c0;
        const float* fp = fB + (size_t)(gy0 + 1) * G + c0;
        float2 q0 = *(const float2*)kp;          // kappa row gy0,   cols c0,c0+1
        float2 q1 = *(const float2*)(kp + G);    // kappa row gy0+1
        float  e0 = lane_shl1(q0.x);             // kappa[gy0,   c0+2]
        float  e1 = lane_shl1(q1.x);             // kappa[gy0+1, c0+2]
        #pragma unroll
        for (int r = 0; r < 8; ++r) {
            const float2 q2 = *(const float2*)(kp + (size_t)(r + 2) * G);
            const float  e2 = lane_shl1(q2.x);
            const float2 fr = *(const float2*)(fp + (size_t)r * G);
            const float f0 = fr.y, f1 = lane_shl1(fr.x);
            const float ke1 = lane_shl1(q1.y);   // kappa[gy+1, c0+3]
            const float inv0 = frcp(2.0f * q1.y + 0.5f * (q0.y + q2.y + q1.x + e1));
            const float inv1 = frcp(2.0f * e1   + 0.5f * (e0 + e2 + q1.y + ke1));
            wN[r] = make_float2(0.5f * (q1.y + q0.y) * inv0, 0.5f * (e1 + e0) * inv1);
            wS[r] = make_float2(0.5f * (q1.y + q2.y) * inv0, 0.5f * (e1 + e2) * inv1);
            wW[r] = make_float2(0.5f * (q1.y + q1.x) * inv0, 0.5f * (e1 + q1.y) * inv1);
            wE[r] = make_float2(0.5f * (q1.y + e1)   * inv0, 0.5f * (e1 + ke1) * inv1);
            Fc[r] = make_float2(f0 * H2 * inv0, f1 * H2 * inv1);
            q0 = q1; q1 = q2; e0 = e1; e1 = e2;
        }
    } else {
        auto gk = [&](int ry, int cx) -> float {
            return ((unsigned)ry < (unsigned)G && (unsigned)cx < (unsigned)G)
                 ? kB[(size_t)ry * G + cx] : 0.0f;
        };
        float qx0 = gk(gy0,     c0), qy0 = gk(gy0,     c0 + 1);
        float qx1 = gk(gy0 + 1, c0), qy1 = gk(gy0 + 1, c0 + 1);
        float e0 = lane_shl1(qx0), e1 = lane_shl1(qx1);
        #pragma unroll
        for (int r = 0; r < 8; ++r) {
            const float qx2 = gk(gy0 + r + 2, c0), qy2 = gk(gy0 + r + 2, c0 + 1);
            const float e2 = lane_shl1(qx2);
            const int ry = gy0 + 1 + r;
            const bool rv = (unsigned)ry < (unsigned)G;
            const float fa = (rv && (unsigned)c0       < (unsigned)G) ? fB[(size_t)ry * G + c0]     : 0.0f;
            const float fb = (rv && (unsigned)(c0 + 1) < (unsigned)G) ? fB[(size_t)ry * G + c0 + 1] : 0.0f;
            const float f0 = fb, f1 = lane_shl1(fa);
            const float ke1 = lane_shl1(qy1);
            const float inv0 = frcp(2.0f * qy1 + 0.5f * (qy0 + qy2 + qx1 + e1));
            const float inv1 = frcp(2.0f * e1  + 0.5f * (e0 + e2 + qy1 + ke1));
            const int gy = gy0 + r;
            const bool dr = (unsigned)gy < (unsigned)Ni;
            const bool d0 = dr && (unsigned)c0       < (unsigned)Ni;
            const bool d1 = dr && (unsigned)(c0 + 1) < (unsigned)Ni;
            wN[r] = make_float2(d0 ? 0.5f * (qy1 + qy0) * inv0 : 0.0f,
                                d1 ? 0.5f * (e1 + e0)   * inv1 : 0.0f);
            wS[r] = make_float2(d0 ? 0.5f * (qy1 + qy2) * inv0 : 0.0f,
                                d1 ? 0.5f * (e1 + e2)   * inv1 : 0.0f);
            wW[r] = make_float2(d0 ? 0.5f * (qy1 + qx1) * inv0 : 0.0f,
                                d1 ? 0.5f * (e1 + qy1)  * inv1 : 0.0f);
            wE[r] = make_float2(d0 ? 0.5f * (qy1 + e1)  * inv0 : 0.0f,
                                d1 ? 0.5f * (e1 + ke1)  * inv1 : 0.0f);
            Fc[r] = make_float2(d0 ? f0 * H2 * inv0 : 0.0f,
                                d1 ? f1 * H2 * inv1 : 0.0f);
            qx0 = qx1; qy0 = qy1; qx1 = qx2; qy1 = qy2; e0 = e1; e1 = e2;
        }
    }

    // ---- u patch (loaded after weights: kappa/f transients are dead) ----
    float2 u[8];
    if (fast) {
        const float* uS = pre + (size_t)b * IMG_P + (size_t)gy0 * Ni + c0;
        #pragma unroll
        for (int r = 0; r < 8; ++r) u[r] = *(const float2*)(uS + (size_t)r * Ni);
    } else {
        const float* uS = pre + (size_t)b * IMG_P;
        #pragma unroll
        for (int r = 0; r < 8; ++r) {
            const int gy = gy0 + r;
            const bool rv = (unsigned)gy < (unsigned)Ni;
            const float a = (rv && (unsigned)c0       < (unsigned)Ni) ? uS[(size_t)gy * Ni + c0]     : 0.0f;
            const float q = (rv && (unsigned)(c0 + 1) < (unsigned)Ni) ? uS[(size_t)gy * Ni + c0 + 1] : 0.0f;
            u[r] = make_float2(a, q);
        }
    }

    // ---- 16 steps; N/S in registers, W/E via DPP, strip edges via dbuf LDS ----
    const int iN = (w > 0)  ? tid - 64 : tid;     // wave w-1's bottom row (clamp: halo-safe)
    const int iS = (w < 15) ? tid + 64 : tid;     // wave w+1's top row
    #pragma unroll
    for (int t = 0; t < 16; ++t) {
        float2* top = ex[t & 1][0];
        float2* bot = ex[t & 1][1];
        top[tid] = u[0];
        bot[tid] = u[7];
        __syncthreads();
        const float2 hN = bot[iN];
        const float2 hS = top[iS];
        float2 pn = hN;
        #pragma unroll
        for (int r = 0; r < 8; ++r) {
            const float2 s = (r < 7) ? u[r + 1] : hS;   // old value (not yet overwritten)
            const float o0 = u[r].x, o1 = u[r].y;
            const float uW = lane_shr1(o1);             // prev lane's col1 = W of col0
            const float uE = lane_shl1(o0);             // next lane's col0 = E of col1
            const float v0 = fmaf(wN[r].x, pn.x,
                             fmaf(wS[r].x, s.x,
                             fmaf(wW[r].x, uW,
                             fmaf(wE[r].x, o1, Fc[r].x))));
            const float v1 = fmaf(wN[r].y, pn.y,
                             fmaf(wS[r].y, s.y,
                             fmaf(wW[r].y, o0,
                             fmaf(wE[r].y, uE, Fc[r].y))));
            pn = make_float2(o0, o1);
            u[r] = make_float2(v0, v1);
        }
    }

    // ---- store valid region rel [16,112)^2: waves 2..13, lanes 8..55 ----
    if (w >= 2 && w < 14 && l >= 8 && l < 56) {
        float* oB = out + (size_t)b * IMG_P;
        if (fast) {
            #pragma unroll
            for (int r = 0; r < 8; ++r)
                *(float2*)(oB + (size_t)(gy0 + r) * Ni + c0) = u[r];
        } else {
            #pragma unroll
            for (int r = 0; r < 8; ++r) {
                const int gy = gy0 + r;
                if ((unsigned)gy < (unsigned)Ni) {
                    if ((unsigned)c0       < (unsigned)Ni) oB[(size_t)gy * Ni + c0]     = u[r].x;
                    if ((unsigned)(c0 + 1) < (unsigned)Ni) oB[(size_t)gy * Ni + c0 + 1] = u[r].y;
                }
            }
        }
    }
}

extern "C" void kernel_launch(void* const* d_in, const int* in_sizes, int n_in,
                              void* d_out, int out_size, void* d_ws, size_t ws_size,
                              hipStream_t stream)
{
    const float* pre = (const float*)d_in[0];
    const float* f   = (const float*)d_in[1];
    const float* kap = (const float*)d_in[2];
    float* out = (float*)d_out;
    (void)d_ws; (void)ws_size;                   // no intermediate buffer needed

    dim3 blk(1024, 1, 1);
    dim3 grd((Ni + TOUT - 1) / TOUT, (Ni + TOUT - 1) / TOUT, 8);   // 11 x 11 x 8

    jac_fused16<<<grd, blk, 0, stream>>>(pre, out, kap, f);
}